// Round 3
// baseline (92.579 us; speedup 1.0000x reference)
//
#include <hip/hip_runtime.h>

// Problem constants (from reference setup_inputs):
//   pred:      [64, 4]     fp32  (d_in[0])
//   fragments: [32, 64, 2] fp32  (d_in[1]) -> 2048 points
//   boundary:  [1, 400, 2] fp32  (d_in[2])
//   out: scalar fp32 = sum_pts min_b( sqdist(pt, box_b boundary) * outside_b ) / 64
#define NBOX 64
#define BP   400
#define NPTS 2048
#define FP   64
#define NBLK 256          // 8 points per block -> exactly 1 block per CU
#define PPB  (NPTS / NBLK)

// Single plain dispatch (cooperative launch crashed graph capture in R2).
// Cross-block completion via a flag handshake instead of grid.sync():
//   - each block computes 8 points' contributions, plain-stores its partial
//     to partials[bid], then RELEASE-stores flags[bid]=1 at agent scope
//     (device-visible across the 8 non-coherent XCD L2s);
//   - block 0's 256 threads ACQUIRE-poll the 256 flags, then reduce.
// Deadlock-free: writers never wait; 256 blocks <= 256 CUs all schedule
// immediately. Poison-robust: flags re-poison to 0xAAAAAAAA != 1 before
// every timed call; and since inputs are constant across calls, even a
// hypothetical stale partial read returns the identical correct value.
__global__ __launch_bounds__(256) void coverage_onedisp(
    const float* __restrict__ pred,       // [64*4]
    const float* __restrict__ frags,      // [2048*2]
    const float* __restrict__ boundary,   // [400*2]
    float* __restrict__ partials,         // ws[0..255]
    unsigned int* __restrict__ flags,     // ws + 4096 B, [256]
    float* __restrict__ out)              // [1]
{
    const int t   = threadIdx.x;
    const int bid = blockIdx.x;
    const int b   = t & 63;   // box index (same mapping in every wave)
    const int j   = t >> 6;   // wave id = BP chunk

    const float lox = pred[4 * b + 0];
    const float loy = pred[4 * b + 1];
    const float hix = pred[4 * b + 2];
    const float hiy = pred[4 * b + 3];
    const float whx = hix - lox;
    const float why = hiy - loy;

    // Stage boundary into LDS once per block: 800 floats = 200 float4.
    __shared__ float4 s_bnd4[BP / 2];     // 200 float4 = 400 (x,y) pairs
    __shared__ float  s_red[256];
    if (t < BP / 2) s_bnd4[t] = ((const float4*)boundary)[t];
    __syncthreads();
    const float2* s_bnd = (const float2*)s_bnd4;

    float bsum = 0.0f;                    // meaningful on t==0 only
    const int k0 = j * (BP / 4);

    #pragma unroll
    for (int i = 0; i < PPB; ++i) {
        const int pt = bid * PPB + i;
        const float px = frags[2 * pt + 0];
        const float py = frags[2 * pt + 1];

        const bool inside = (px >= lox) && (py >= loy) && (hix >= px) && (hiy >= py);
        // inside depends only on (lane's box, point) -> identical ballot in
        // all 4 waves -> block-uniform branch (safe vs the barriers below).
        if (__ballot(inside) != 0ULL) continue;   // this point contributes 0

        const float ax = px - lox;        // dx = ax - bx*whx
        const float ay = py - loy;
        float mind = 1e30f;
        #pragma unroll 5
        for (int k = 0; k < BP / 4; ++k) {
            const float2 bxy = s_bnd[k0 + k];     // wave-uniform addr -> broadcast
            const float dx = fmaf(-whx, bxy.x, ax);
            const float dy = fmaf(-why, bxy.y, ay);
            const float d  = fmaf(dy, dy, dx * dx);
            mind = fminf(mind, d);
        }

        // Min across the 4 waves per box (LDS), then across 64 boxes (shuffle).
        s_red[t] = mind;
        __syncthreads();
        if (t < 64) {
            float v = fminf(fminf(s_red[t], s_red[t + 64]),
                            fminf(s_red[t + 128], s_red[t + 192]));
            #pragma unroll
            for (int off = 32; off; off >>= 1)
                v = fminf(v, __shfl_down(v, off));
            if (t == 0) bsum += v;
        }
        __syncthreads();                  // s_red reused next point
    }

    if (t == 0) {
        __hip_atomic_store(&partials[bid], bsum,
                           __ATOMIC_RELAXED, __HIP_MEMORY_SCOPE_AGENT);
        __hip_atomic_store(&flags[bid], 1u,
                           __ATOMIC_RELEASE, __HIP_MEMORY_SCOPE_AGENT);
    }

    if (bid == 0) {                       // block-uniform branch
        // Thread t waits for block t's flag, then reads its partial.
        while (__hip_atomic_load(&flags[t], __ATOMIC_ACQUIRE,
                                 __HIP_MEMORY_SCOPE_AGENT) != 1u) {
            __builtin_amdgcn_s_sleep(1);  // back off the L2 while polling
        }
        float s = __hip_atomic_load(&partials[t], __ATOMIC_RELAXED,
                                    __HIP_MEMORY_SCOPE_AGENT);
        #pragma unroll
        for (int off = 32; off; off >>= 1)
            s += __shfl_down(s, off);
        if ((t & 63) == 0) s_red[t >> 6] = s;
        __syncthreads();
        if (t == 0)
            out[0] = (s_red[0] + s_red[1] + s_red[2] + s_red[3]) * (1.0f / (float)FP);
    }
}

extern "C" void kernel_launch(void* const* d_in, const int* in_sizes, int n_in,
                              void* d_out, int out_size, void* d_ws, size_t ws_size,
                              hipStream_t stream) {
    const float* pred     = (const float*)d_in[0];
    const float* frags    = (const float*)d_in[1];
    const float* boundary = (const float*)d_in[2];
    float*        partials = (float*)d_ws;
    unsigned int* flags    = (unsigned int*)((char*)d_ws + 4096);
    float* out = (float*)d_out;

    coverage_onedisp<<<NBLK, 256, 0, stream>>>(pred, frags, boundary,
                                               partials, flags, out);
}

// Round 4
// 72.218 us; speedup vs baseline: 1.2820x; 1.2820x over previous
//
#include <hip/hip_runtime.h>

// Problem constants (from reference setup_inputs):
//   pred:      [64, 4]     fp32  (d_in[0])
//   fragments: [32, 64, 2] fp32  (d_in[1]) -> 2048 points
//   boundary:  [1, 400, 2] fp32  (d_in[2])
//   out: scalar fp32 = sum_pts min_b( sqdist(pt, box_b boundary) * outside_b ) / 64
//
// Measured structure facts (R0-R3 on MI355X):
//   - harness poisons the 256 MiB d_ws every timed call: 39.5 us at 85% of
//     HBM peak (fill roofline), present even if we never touch d_ws;
//   - ~200 harness reset dispatches per iteration (dispatch-ID gaps) ~= 30 us;
//   - cross-block flag polling costs ~35 us (R3); cooperative launch crashes
//     graph capture (R2); single-address device atomics ~= plain stores (R0).
// => the two-dispatch plain-store structure below is the measured optimum.
#define NBOX 64
#define BP   400
#define NPTS 2048
#define FP   64

// K1: one block per fragment point, 256 thr = 4 waves.
// lane (t&63) owns box (t&63) (same mapping in every wave -> block-uniform
// ballot); wave (t>>6) covers a 100-sample chunk of BP.
// Every block plain-stores its per-point contribution (or 0) to ws[pt], so
// all 2048 slots are written each call and the 0xAA ws-poison is never read.
__global__ __launch_bounds__(256) void point_min_kernel(
    const float* __restrict__ pred,      // [64*4]
    const float* __restrict__ frags,     // [2048*2]
    const float* __restrict__ boundary,  // [400*2]
    float* __restrict__ ws)              // [2048] per-point min (0 if inside)
{
    const int t  = threadIdx.x;
    const int pt = blockIdx.x;
    const int b  = t & 63;   // box index
    const int j  = t >> 6;   // wave id = BP chunk

    const float px = frags[2 * pt + 0];
    const float py = frags[2 * pt + 1];

    const float lox = pred[4 * b + 0];
    const float loy = pred[4 * b + 1];
    const float hix = pred[4 * b + 2];
    const float hiy = pred[4 * b + 3];

    const bool inside = (px >= lox) && (py >= loy) && (hix >= px) && (hiy >= py);
    // Identical ballot in all 4 waves -> block-uniform branch (safe vs barrier).
    if (__ballot(inside) != 0ULL) {      // contribution exactly 0
        if (t == 0) ws[pt] = 0.0f;
        return;
    }

    // Stage boundary into LDS: 800 floats = 200 float4, one vec-load per thread.
    __shared__ float4 s_bnd4[BP / 2];        // 200 float4 = 400 (x,y) pairs
    __shared__ float  s_red[256];
    if (t < BP / 2) s_bnd4[t] = ((const float4*)boundary)[t];
    __syncthreads();

    const float whx = hix - lox;
    const float why = hiy - loy;
    const float ax  = px - lox;              // dx = ax - bx*whx
    const float ay  = py - loy;

    const float2* s_bnd = (const float2*)s_bnd4;
    float mind = 1e30f;
    const int k0 = j * (BP / 4);
    #pragma unroll 5
    for (int k = 0; k < BP / 4; ++k) {
        const float2 bxy = s_bnd[k0 + k];    // wave-uniform addr -> broadcast
        const float dx = fmaf(-whx, bxy.x, ax);
        const float dy = fmaf(-why, bxy.y, ay);
        const float d  = fmaf(dy, dy, dx * dx);
        mind = fminf(mind, d);
    }

    // Min across the 4 waves per box (LDS), then across 64 boxes (shuffle).
    s_red[t] = mind;
    __syncthreads();
    if (t < 64) {
        float v = fminf(fminf(s_red[t], s_red[t + 64]),
                        fminf(s_red[t + 128], s_red[t + 192]));
        #pragma unroll
        for (int off = 32; off; off >>= 1)
            v = fminf(v, __shfl_down(v, off));
        if (t == 0) ws[pt] = v;              // plain store, no atomic
    }
}

// K2: one block sums ws[0..2047] and writes out = sum / FP. Deterministic
// tree reduction; out is written unconditionally so d_out needs no memset.
__global__ __launch_bounds__(256) void reduce_kernel(
    const float* __restrict__ ws,        // [2048]
    float* __restrict__ out)             // [1]
{
    const int t = threadIdx.x;
    // 2048 floats = 512 float4; 256 threads x 2 float4 each.
    const float4* w4 = (const float4*)ws;
    const float4 a = w4[t];
    const float4 c = w4[t + 256];
    float s = (a.x + a.y) + (a.z + a.w) + (c.x + c.y) + (c.z + c.w);
    #pragma unroll
    for (int off = 32; off; off >>= 1)
        s += __shfl_down(s, off);
    __shared__ float sr[4];
    if ((t & 63) == 0) sr[t >> 6] = s;
    __syncthreads();
    if (t == 0)
        out[0] = (sr[0] + sr[1] + sr[2] + sr[3]) * (1.0f / (float)FP);
}

extern "C" void kernel_launch(void* const* d_in, const int* in_sizes, int n_in,
                              void* d_out, int out_size, void* d_ws, size_t ws_size,
                              hipStream_t stream) {
    const float* pred     = (const float*)d_in[0];
    const float* frags    = (const float*)d_in[1];
    const float* boundary = (const float*)d_in[2];
    float* ws  = (float*)d_ws;
    float* out = (float*)d_out;

    // No memset node: out is written unconditionally by reduce_kernel, and
    // every ws slot K2 reads is written by K1 first.
    point_min_kernel<<<NPTS, 256, 0, stream>>>(pred, frags, boundary, ws);
    reduce_kernel<<<1, 256, 0, stream>>>(ws, out);
}